// Round 1
// baseline (3198.860 us; speedup 1.0000x reference)
//
#include <hip/hip_runtime.h>
#include <hip/hip_fp16.h>

#define DEV __device__ __forceinline__

typedef __attribute__((ext_vector_type(8))) _Float16 half8;
typedef __attribute__((ext_vector_type(4))) _Float16 half4;
typedef __attribute__((ext_vector_type(4))) float floatx4;

static constexpr int M = 2048;
static constexpr int N = 32768;
static constexpr int K = 4096;

DEV void async_copy16(void* lds, const void* g) {
  __builtin_amdgcn_global_load_lds(
      (const __attribute__((address_space(1))) unsigned int*)g,
      (__attribute__((address_space(3))) unsigned int*)lds, 16, 0, 0);
}

// ---------------- prep_x: A1 = fp16((x-b_dec)*2^-5), A2 = fp16(resid*2^7) ----
__global__ void prep_x(const float* __restrict__ x, const float* __restrict__ b_dec,
                       _Float16* __restrict__ A1, _Float16* __restrict__ A2) {
  int i = blockIdx.x * blockDim.x + threadIdx.x;
  int idx = i * 4;
  float4 xv = *(const float4*)(x + idx);
  float4 bd = *(const float4*)(b_dec + (idx & (K - 1)));
  float c[4] = {xv.x - bd.x, xv.y - bd.y, xv.z - bd.z, xv.w - bd.w};
  half4 a1, a2;
#pragma unroll
  for (int j = 0; j < 4; ++j) {
    float s = c[j] * 0.03125f;                       // x * 2^-5
    _Float16 h1 = (_Float16)s;
    a1[j] = h1;
    a2[j] = (_Float16)((s - (float)h1) * 4096.0f);   // residual * 2^12 -> x2*2^7
  }
  *(half4*)(A1 + idx) = a1;
  *(half4*)(A2 + idx) = a2;
}

// ------------- prep_w: transpose W to [N][K], split W1=fp16(w*32), W2=fp16(resid*4096)
__global__ void prep_w(const float* __restrict__ W, _Float16* __restrict__ W1T,
                       _Float16* __restrict__ W2T) {
  __shared__ float tile[64][68];
  int tid = threadIdx.x;
  int tn = blockIdx.x & 511, tk = blockIdx.x >> 9;
  int k0 = tk * 64, n0 = tn * 64;
#pragma unroll
  for (int p = 0; p < 4; ++p) {
    int row = p * 16 + (tid >> 4);
    int col = (tid & 15) * 4;
    float4 v = *(const float4*)(W + (size_t)(k0 + row) * N + n0 + col);
    tile[row][col] = v.x; tile[row][col + 1] = v.y;
    tile[row][col + 2] = v.z; tile[row][col + 3] = v.w;
  }
  __syncthreads();
  int nl = tid >> 2, kc = (tid & 3) * 16;
  half8 v1[2], v2[2];
#pragma unroll
  for (int j = 0; j < 16; ++j) {
    float w = tile[kc + j][nl] * 32.0f;              // w * 2^5
    _Float16 h1 = (_Float16)w;
    _Float16 h2 = (_Float16)((w - (float)h1) * 4096.0f);  // w2 * 2^17
    v1[j >> 3][j & 7] = h1;
    v2[j >> 3][j & 7] = h2;
  }
  size_t off = (size_t)(n0 + nl) * K + k0 + kc;
  *(half8*)(W1T + off) = v1[0];
  *(half8*)(W1T + off + 8) = v1[1];
  *(half8*)(W2T + off) = v2[0];
  *(half8*)(W2T + off + 8) = v2[1];
}

// ---------------- GEMM: out (+)= scale * A@B^T  (+ b_enc when init) ------------
// A [M][K] half row-major, B [N][K] half row-major (i.e. W^T). 128x128 tile, BK=64.
__global__ __launch_bounds__(256) void gemm(
    const _Float16* __restrict__ Aa, const _Float16* __restrict__ Ba,
    const _Float16* __restrict__ Ab, const _Float16* __restrict__ Bb,
    int nchunks, float scale, int initmode,
    const float* __restrict__ b_enc, float* __restrict__ out) {
  __shared__ __align__(16) _Float16 lA[128 * 64];
  __shared__ __align__(16) _Float16 lB[128 * 64];
  const int tid = threadIdx.x;
  const int lane = tid & 63, wave = tid >> 6;
  const int wm = wave & 1, wn = wave >> 1;
  const int m0 = (blockIdx.x & 15) * 128, n0 = (blockIdx.x >> 4) * 128;

  floatx4 acc[4][4];
#pragma unroll
  for (int a = 0; a < 4; ++a)
#pragma unroll
    for (int b = 0; b < 4; ++b) acc[a][b] = (floatx4){0.f, 0.f, 0.f, 0.f};

  const int srow = lane >> 3;   // row within 8-row staging chunk
  const int spos = lane & 7;    // 16B slot within row
  const int quad = lane >> 4, l16 = lane & 15;

  for (int c = 0; c < nchunks; ++c) {
    const _Float16* Abase = c ? Ab : Aa;
    const _Float16* Bbase = c ? Bb : Ba;
    for (int kk = 0; kk < K; kk += 64) {
#pragma unroll
      for (int i = 0; i < 4; ++i) {
        int ci = wave * 4 + i;          // 16 chunks of 8 rows each
        int r = ci * 8 + srow;
        int ca = spos ^ srow;           // XOR swizzle on the global side
        async_copy16(&lA[ci * 512], Abase + (size_t)(m0 + r) * K + kk + ca * 8);
        async_copy16(&lB[ci * 512], Bbase + (size_t)(n0 + r) * K + kk + ca * 8);
      }
      __syncthreads();
#pragma unroll
      for (int s = 0; s < 2; ++s) {
        half8 af[4], bf[4];
#pragma unroll
        for (int f = 0; f < 4; ++f) {
          int row = wm * 64 + f * 16 + l16;
          int ch = ((s << 2) + quad) ^ (row & 7);
          af[f] = *(const half8*)&lA[row * 64 + ch * 8];
        }
#pragma unroll
        for (int f = 0; f < 4; ++f) {
          int row = wn * 64 + f * 16 + l16;
          int ch = ((s << 2) + quad) ^ (row & 7);
          bf[f] = *(const half8*)&lB[row * 64 + ch * 8];
        }
#pragma unroll
        for (int fm = 0; fm < 4; ++fm)
#pragma unroll
          for (int fn = 0; fn < 4; ++fn)
            acc[fm][fn] = __builtin_amdgcn_mfma_f32_16x16x32_f16(
                af[fm], bf[fn], acc[fm][fn], 0, 0, 0);
      }
      __syncthreads();
    }
  }
  float bv[4];
  if (initmode) {
#pragma unroll
    for (int fn = 0; fn < 4; ++fn) bv[fn] = b_enc[n0 + wn * 64 + fn * 16 + l16];
  }
#pragma unroll
  for (int fm = 0; fm < 4; ++fm) {
    int rbase = m0 + wm * 64 + fm * 16 + quad * 4;   // C/D: col=lane&15, row=quad*4+i
#pragma unroll
    for (int i = 0; i < 4; ++i) {
      float* orow = out + (size_t)(rbase + i) * N + n0 + wn * 64 + l16;
#pragma unroll
      for (int fn = 0; fn < 4; ++fn) {
        float v = acc[fm][fn][i] * scale;
        if (initmode) orow[fn * 16] = v + bv[fn];
        else orow[fn * 16] += v;
      }
    }
  }
}

// ---------------- per-row top-64 select + sparsify (in place on d_out) ---------
__global__ void select_topk(float* __restrict__ out) {
  __shared__ int hist[2048];
  __shared__ float cval[2048];
  __shared__ int cidx[2048];
  __shared__ int gsum[256];
  __shared__ int Tbin, cnt;
  __shared__ float bestV[4];
  __shared__ int bestI[4], bestS[4];
  __shared__ int selIdx[64];
  __shared__ float selVal[64];

  const int tid = threadIdx.x;
  float* rp = out + (size_t)blockIdx.x * N;

  for (int j = tid; j < 2048; j += 256) hist[j] = 0;
  if (tid == 0) { Tbin = 1; cnt = 0; }
  __syncthreads();
  // histogram on positive-float bit keys (monotone)
  for (int j = tid; j < N; j += 256) {
    float v = rp[j];
    if (v > 0.f) atomicAdd(&hist[__float_as_uint(v) >> 20], 1);
  }
  __syncthreads();
  int own = 0;
#pragma unroll
  for (int j = 0; j < 8; ++j) own += hist[tid * 8 + j];
  gsum[tid] = own;
  __syncthreads();
  for (int off = 1; off < 256; off <<= 1) {   // suffix scan over group sums
    int add = (tid + off < 256) ? gsum[tid + off] : 0;
    __syncthreads();
    gsum[tid] += add;
    __syncthreads();
  }
  int acc = gsum[tid] - own;                  // count of keys >= (tid+1)*8
  for (int j = 7; j >= 0; --j) {
    int h = hist[tid * 8 + j];
    acc += h;
    if (acc >= 64 && acc - h < 64) Tbin = tid * 8 + j;  // unique crossing bin
  }
  __syncthreads();
  unsigned T = (unsigned)Tbin;
  for (int j = tid; j < N; j += 256) {        // collect candidates
    float v = rp[j];
    if (v > 0.f && (__float_as_uint(v) >> 20) >= T) {
      int p = atomicAdd(&cnt, 1);
      if (p < 2048) { cval[p] = v; cidx[p] = j; }
    }
  }
  __syncthreads();
  int nc = cnt < 2048 ? cnt : 2048;
  int nsel = nc < 64 ? nc : 64;
  for (int r = 0; r < nsel; ++r) {            // 64 argmax rounds, tie -> lower idx
    float bvv = -1.f;
    int bi = 0x7fffffff, bs = -1;
    for (int j = tid; j < nc; j += 256) {
      float v = cval[j];
      int id = cidx[j];
      if (v > bvv || (v == bvv && id < bi)) { bvv = v; bi = id; bs = j; }
    }
    for (int off = 32; off >= 1; off >>= 1) {
      float ov = __shfl_down(bvv, off);
      int oi = __shfl_down(bi, off);
      int os = __shfl_down(bs, off);
      if (ov > bvv || (ov == bvv && oi < bi)) { bvv = ov; bi = oi; bs = os; }
    }
    if ((tid & 63) == 0) { bestV[tid >> 6] = bvv; bestI[tid >> 6] = bi; bestS[tid >> 6] = bs; }
    __syncthreads();
    if (tid == 0) {
      float fv = bestV[0];
      int fi = bestI[0], fs = bestS[0];
      for (int w = 1; w < 4; ++w)
        if (bestV[w] > fv || (bestV[w] == fv && bestI[w] < fi)) {
          fv = bestV[w]; fi = bestI[w]; fs = bestS[w];
        }
      selIdx[r] = fi; selVal[r] = fv;
      cval[fs] = -1.f;                        // remove winner
    }
    __syncthreads();
  }
  float4 z = {0.f, 0.f, 0.f, 0.f};
  float4* rp4 = (float4*)rp;
  for (int j = tid; j < N / 4; j += 256) rp4[j] = z;
  __syncthreads();
  if (tid < nsel) rp[selIdx[tid]] = selVal[tid];
}

extern "C" void kernel_launch(void* const* d_in, const int* in_sizes, int n_in,
                              void* d_out, int out_size, void* d_ws, size_t ws_size,
                              hipStream_t stream) {
  const float* x = (const float*)d_in[0];
  const float* W = (const float*)d_in[1];
  const float* b_enc = (const float*)d_in[2];
  const float* b_dec = (const float*)d_in[3];
  float* out = (float*)d_out;

  _Float16* A1 = (_Float16*)d_ws;                 // 16 MB
  _Float16* A2 = A1 + (size_t)M * K;              // 16 MB
  _Float16* W1T = A2 + (size_t)M * K;             // 256 MB
  _Float16* W2T = W1T + (size_t)N * K;            // 256 MB  (total ~545 MB)

  prep_x<<<(M * K / 4) / 256, 256, 0, stream>>>(x, b_dec, A1, A2);
  prep_w<<<(N / 64) * (K / 64), 256, 0, stream>>>(W, W1T, W2T);
  // L1: small terms (A1*W2 + A2*W1), scale 2^-12, initializes out with b_enc
  gemm<<<(M / 128) * (N / 128), 256, 0, stream>>>(A1, W2T, A2, W1T, 2,
                                                  1.0f / 4096.0f, 1, b_enc, out);
  // L2: big term A1*W1, scale 1, accumulates
  gemm<<<(M / 128) * (N / 128), 256, 0, stream>>>(A1, W1T, nullptr, nullptr, 1,
                                                  1.0f, 0, b_enc, out);
  select_topk<<<M, 256, 0, stream>>>(out);
}

// Round 2
// 2303.794 us; speedup vs baseline: 1.3885x; 1.3885x over previous
//
#include <hip/hip_runtime.h>
#include <hip/hip_fp16.h>

#define DEV __device__ __forceinline__

typedef __attribute__((ext_vector_type(8))) _Float16 half8;
typedef __attribute__((ext_vector_type(4))) _Float16 half4;
typedef __attribute__((ext_vector_type(4))) float floatx4;

static constexpr int M = 2048;
static constexpr int N = 32768;
static constexpr int K = 4096;

DEV void async_copy16(void* lds, const void* g) {
  __builtin_amdgcn_global_load_lds(
      (const __attribute__((address_space(1))) unsigned int*)g,
      (__attribute__((address_space(3))) unsigned int*)lds, 16, 0, 0);
}

// ---------------- prep_x: A1 = fp16((x-b_dec)*2^-5), A2 = fp16(resid*2^12) ----
__global__ void prep_x(const float* __restrict__ x, const float* __restrict__ b_dec,
                       _Float16* __restrict__ A1, _Float16* __restrict__ A2) {
  int i = blockIdx.x * blockDim.x + threadIdx.x;
  int idx = i * 4;
  float4 xv = *(const float4*)(x + idx);
  float4 bd = *(const float4*)(b_dec + (idx & (K - 1)));
  float c[4] = {xv.x - bd.x, xv.y - bd.y, xv.z - bd.z, xv.w - bd.w};
  half4 a1, a2;
#pragma unroll
  for (int j = 0; j < 4; ++j) {
    float s = c[j] * 0.03125f;                       // x * 2^-5
    _Float16 h1 = (_Float16)s;
    a1[j] = h1;
    a2[j] = (_Float16)((s - (float)h1) * 4096.0f);   // residual * 2^12
  }
  *(half4*)(A1 + idx) = a1;
  *(half4*)(A2 + idx) = a2;
}

// ------------- prep_w: transpose W to [N][K], split W1=fp16(w*32), W2=fp16(resid*4096)
__global__ void prep_w(const float* __restrict__ W, _Float16* __restrict__ W1T,
                       _Float16* __restrict__ W2T) {
  __shared__ float tile[64][68];
  int tid = threadIdx.x;
  int tn = blockIdx.x & 511, tk = blockIdx.x >> 9;
  int k0 = tk * 64, n0 = tn * 64;
#pragma unroll
  for (int p = 0; p < 4; ++p) {
    int row = p * 16 + (tid >> 4);
    int col = (tid & 15) * 4;
    float4 v = *(const float4*)(W + (size_t)(k0 + row) * N + n0 + col);
    tile[row][col] = v.x; tile[row][col + 1] = v.y;
    tile[row][col + 2] = v.z; tile[row][col + 3] = v.w;
  }
  __syncthreads();
  int nl = tid >> 2, kc = (tid & 3) * 16;
  half8 v1[2], v2[2];
#pragma unroll
  for (int j = 0; j < 16; ++j) {
    float w = tile[kc + j][nl] * 32.0f;              // w * 2^5
    _Float16 h1 = (_Float16)w;
    _Float16 h2 = (_Float16)((w - (float)h1) * 4096.0f);
    v1[j >> 3][j & 7] = h1;
    v2[j >> 3][j & 7] = h2;
  }
  size_t off = (size_t)(n0 + nl) * K + k0 + kc;
  *(half8*)(W1T + off) = v1[0];
  *(half8*)(W1T + off + 8) = v1[1];
  *(half8*)(W2T + off) = v2[0];
  *(half8*)(W2T + off + 8) = v2[1];
}

// ---------------- gemm1: out = A1 @ W1T^T + b_enc  (single K=4096 pass) -------
__global__ __launch_bounds__(256) void gemm1(
    const _Float16* __restrict__ A, const _Float16* __restrict__ B,
    const float* __restrict__ b_enc, float* __restrict__ out) {
  __shared__ __align__(16) _Float16 lA[128 * 64];
  __shared__ __align__(16) _Float16 lB[128 * 64];
  const int tid = threadIdx.x;
  const int lane = tid & 63, wave = tid >> 6;
  const int wm = wave & 1, wn = wave >> 1;
  const int m0 = (blockIdx.x & 15) * 128, n0 = (blockIdx.x >> 4) * 128;

  floatx4 acc[4][4];
#pragma unroll
  for (int a = 0; a < 4; ++a)
#pragma unroll
    for (int b = 0; b < 4; ++b) acc[a][b] = (floatx4){0.f, 0.f, 0.f, 0.f};

  const int srow = lane >> 3;
  const int spos = lane & 7;
  const int quad = lane >> 4, l16 = lane & 15;

  for (int kk = 0; kk < K; kk += 64) {
#pragma unroll
    for (int i = 0; i < 4; ++i) {
      int ci = wave * 4 + i;
      int r = ci * 8 + srow;
      int ca = spos ^ srow;           // XOR swizzle on the global side
      async_copy16(&lA[ci * 512], A + (size_t)(m0 + r) * K + kk + ca * 8);
      async_copy16(&lB[ci * 512], B + (size_t)(n0 + r) * K + kk + ca * 8);
    }
    __syncthreads();
#pragma unroll
    for (int s = 0; s < 2; ++s) {
      half8 af[4], bf[4];
#pragma unroll
      for (int f = 0; f < 4; ++f) {
        int row = wm * 64 + f * 16 + l16;
        int ch = ((s << 2) + quad) ^ (row & 7);
        af[f] = *(const half8*)&lA[row * 64 + ch * 8];
      }
#pragma unroll
      for (int f = 0; f < 4; ++f) {
        int row = wn * 64 + f * 16 + l16;
        int ch = ((s << 2) + quad) ^ (row & 7);
        bf[f] = *(const half8*)&lB[row * 64 + ch * 8];
      }
#pragma unroll
      for (int fm = 0; fm < 4; ++fm)
#pragma unroll
        for (int fn = 0; fn < 4; ++fn)
          acc[fm][fn] = __builtin_amdgcn_mfma_f32_16x16x32_f16(
              af[fm], bf[fn], acc[fm][fn], 0, 0, 0);
    }
    __syncthreads();
  }
  float bv[4];
#pragma unroll
  for (int fn = 0; fn < 4; ++fn) bv[fn] = b_enc[n0 + wn * 64 + fn * 16 + l16];
#pragma unroll
  for (int fm = 0; fm < 4; ++fm) {
    int rbase = m0 + wm * 64 + fm * 16 + quad * 4;   // C/D: col=lane&15, row=quad*4+i
#pragma unroll
    for (int i = 0; i < 4; ++i) {
      float* orow = out + (size_t)(rbase + i) * N + n0 + wn * 64 + l16;
#pragma unroll
      for (int fn = 0; fn < 4; ++fn) orow[fn * 16] = acc[fm][fn][i] + bv[fn];
    }
  }
}

// ------- select_refine: per row, find candidates near top-64 boundary from pre1
// (in d_out), recompute them exactly via split fp32 dots, rank, zero row, scatter.
__global__ __launch_bounds__(256) void select_refine(
    const _Float16* __restrict__ A1, const _Float16* __restrict__ A2,
    const _Float16* __restrict__ W1T, const _Float16* __restrict__ W2T,
    const float* __restrict__ b_enc, float* __restrict__ out) {
  __shared__ int hist[4096];
  __shared__ __align__(16) _Float16 a1r[4096];
  __shared__ __align__(16) _Float16 a2r[4096];
  __shared__ float cval[256];
  __shared__ int cidx[256];
  __shared__ int gsum[256];
  __shared__ int Tbin, cnt;

  const int tid = threadIdx.x;
  const int row = blockIdx.x;
  float* rp = out + (size_t)row * N;

  // A-row splits -> LDS
  const half8* a1g = (const half8*)(A1 + (size_t)row * K);
  const half8* a2g = (const half8*)(A2 + (size_t)row * K);
  for (int j = tid; j < K / 8; j += 256) {
    ((half8*)a1r)[j] = a1g[j];
    ((half8*)a2r)[j] = a2g[j];
  }
  for (int j = tid; j < 4096; j += 256) hist[j] = 0;
  if (tid == 0) { Tbin = 1; cnt = 0; }
  __syncthreads();

  // histogram on positive-float bit keys (monotone), 4096 bins
  for (int j = tid; j < N; j += 256) {
    float v = rp[j];
    if (v > 0.f) atomicAdd(&hist[__float_as_uint(v) >> 19], 1);
  }
  __syncthreads();
  int own = 0;
#pragma unroll
  for (int j = 0; j < 16; ++j) own += hist[tid * 16 + j];
  gsum[tid] = own;
  __syncthreads();
  for (int off = 1; off < 256; off <<= 1) {   // suffix scan over group sums
    int add = (tid + off < 256) ? gsum[tid + off] : 0;
    __syncthreads();
    gsum[tid] += add;
    __syncthreads();
  }
  int acc = gsum[tid] - own;                  // count of keys >= (tid+1)*16
  for (int j = 15; j >= 0; --j) {
    int h = hist[tid * 16 + j];
    acc += h;
    if (acc >= 64 && acc - h < 64) Tbin = tid * 16 + j;  // bin of rank-64 value
  }
  __syncthreads();
  // margin: true top-64 has pre1 >= bin_edge - 2*maxerr; delta=0.01 is ~20 sigma
  float thr = __uint_as_float((unsigned)Tbin << 19) - 0.01f;
  for (int j = tid; j < N; j += 256) {
    float v = rp[j];
    if (v > 0.f && v >= thr) {
      int p = atomicAdd(&cnt, 1);
      if (p < 256) cidx[p] = j;
    }
  }
  __syncthreads();
  const int nc = cnt < 256 ? cnt : 256;

  // refine: one wave per candidate, exact fp32 split dot over K=4096
  const int wave = tid >> 6, lane = tid & 63;
  for (int c = wave; c < nc; c += 4) {
    const int col = cidx[c];
    const half8* w1 = (const half8*)(W1T + (size_t)col * K);
    const half8* w2 = (const half8*)(W2T + (size_t)col * K);
    float a = 0.f;
#pragma unroll
    for (int j = 0; j < 8; ++j) {
      int off = j * 64 + lane;                // coalesced 1KB per wave per j
      half8 hw1 = w1[off], hw2 = w2[off];
      half8 ha1 = ((const half8*)a1r)[off], ha2 = ((const half8*)a2r)[off];
#pragma unroll
      for (int e = 0; e < 8; ++e) {
        float sx = fmaf((float)ha2[e], 2.44140625e-4f, (float)ha1[e]);
        float tw = fmaf((float)hw2[e], 2.44140625e-4f, (float)hw1[e]);
        a = fmaf(sx, tw, a);
      }
    }
#pragma unroll
    for (int off = 32; off >= 1; off >>= 1) a += __shfl_xor(a, off);
    if (lane == 0) cval[c] = a + b_enc[col];
  }
  __syncthreads();

  // zero the row, then scatter top-64 by exact rank (ties -> lower index)
  float4 z = {0.f, 0.f, 0.f, 0.f};
  float4* rp4 = (float4*)rp;
  for (int j = tid; j < N / 4; j += 256) rp4[j] = z;
  __syncthreads();
  if (tid < nc) {
    float vi = cval[tid];
    int ii = cidx[tid];
    int rank = 0;
    for (int j = 0; j < nc; ++j) {
      float vj = cval[j];                     // LDS broadcast
      rank += (vj > vi) || (vj == vi && cidx[j] < ii);
    }
    if (rank < 64) rp[ii] = vi;
  }
}

extern "C" void kernel_launch(void* const* d_in, const int* in_sizes, int n_in,
                              void* d_out, int out_size, void* d_ws, size_t ws_size,
                              hipStream_t stream) {
  const float* x = (const float*)d_in[0];
  const float* W = (const float*)d_in[1];
  const float* b_enc = (const float*)d_in[2];
  const float* b_dec = (const float*)d_in[3];
  float* out = (float*)d_out;

  _Float16* A1 = (_Float16*)d_ws;                 // 16 MB
  _Float16* A2 = A1 + (size_t)M * K;              // 16 MB
  _Float16* W1T = A2 + (size_t)M * K;             // 256 MB
  _Float16* W2T = W1T + (size_t)N * K;            // 256 MB  (total ~544 MB)

  prep_x<<<(M * K / 4) / 256, 256, 0, stream>>>(x, b_dec, A1, A2);
  prep_w<<<(N / 64) * (K / 64), 256, 0, stream>>>(W, W1T, W2T);
  gemm1<<<(M / 128) * (N / 128), 256, 0, stream>>>(A1, W1T, b_enc, out);
  select_refine<<<M, 256, 0, stream>>>(A1, A2, W1T, W2T, b_enc, out);
}